// Round 13
// baseline (127.003 us; speedup 1.0000x reference)
//
#include <hip/hip_runtime.h>
#include <hip/hip_bf16.h>

// MLPPredictor: score[e] = W2 . relu(W1 @ concat(h[src],h[dst]) + b1) + b2
// SETTLED (R0-R12): h/W1/b1/W2/b2 = fp32, src/dst = int32, out = fp32.
// R12 (PASSED, 122 us): fused gemm_uw_f (MFMA + LDS-reuse int8 quant) +
// edge_score_q (int8 gather). Edge ~27 us vs 153.6 MB / 6.5 TB/s ~ 23.6 us
// floor. R13: edge moves to 8 lanes/edge with uint4 (16B) gathers — halves
// VMEM instructions/byte, doubles in-flight bytes/lane. EPG stays 4,
// single-writer float4 store, default launch bounds (avoids all three
// R8-ghost suspects). gemm_uw_f unchanged (R12-proven).
// MFMA fragment maps (probe-verified on gfx950, R5 mode 0):
//   A: lane holds A[m=lane&15][k=(lane>>4)*8+j]
//   B: lane holds B[k=(lane>>4)*8+j][n=lane&15]
//   D: lane reg r holds D[row=(lane>>4)*4+r][col=lane&15]

typedef __attribute__((ext_vector_type(8))) short short8;   // 8 bf16
typedef __attribute__((ext_vector_type(4))) float floatx4;  // MFMA acc

constexpr int HF = 128;   // H_FEATS
constexpr int K2 = 256;   // 2*H

union BF8 { short8 v; unsigned short s[8]; __hip_bfloat16 e[8]; };
union I16 { uint4 v; signed char c[16]; };

__device__ __forceinline__ short8 pack_bf16_8(float4 a, float4 b) {
    BF8 u;
    u.e[0] = __float2bfloat16(a.x); u.e[1] = __float2bfloat16(a.y);
    u.e[2] = __float2bfloat16(a.z); u.e[3] = __float2bfloat16(a.w);
    u.e[4] = __float2bfloat16(b.x); u.e[5] = __float2bfloat16(b.y);
    u.e[6] = __float2bfloat16(b.z); u.e[7] = __float2bfloat16(b.w);
    return u.v;
}

__device__ __forceinline__ float bf2f(unsigned short s) {
    union { unsigned u; float f; } c; c.u = (unsigned)s << 16; return c.f;
}

__device__ __forceinline__ unsigned short f2bf(float x) {
    return (unsigned short)__bfloat16_as_ushort(__float2bfloat16(x));
}

// pack 8 floats (|v[i]*inv| <= 127) into 8 int8 bytes (byte k = v[k])
__device__ __forceinline__ uint2 quant8(const float* v, float inv) {
    unsigned w0 = 0, w1 = 0;
    #pragma unroll
    for (int i = 0; i < 4; ++i)
        w0 |= ((unsigned)((int)rintf(v[i] * inv) & 0xFF)) << (8 * i);
    #pragma unroll
    for (int i = 0; i < 4; ++i)
        w1 |= ((unsigned)((int)rintf(v[4 + i] * inv) & 0xFF)) << (8 * i);
    return make_uint2(w0, w1);
}

// ==== 1) fused: per-node GEMM + LDS round-trip + int8 quant (R12 verbatim) ====
__global__ __launch_bounds__(256, 2) void gemm_uw_f(
    const float* __restrict__ h,
    const float* __restrict__ W1,
    const float* __restrict__ b1,
    char* __restrict__ u8,               // [n_nodes][128] int8 (u incl. +b1)
    char* __restrict__ w8,               // [n_nodes][128] int8
    float* __restrict__ su,              // [n_nodes] scale for u
    float* __restrict__ sw,              // [n_nodes] scale for w
    const int n_nodes)
{
    __shared__ __hip_bfloat16 sW[HF * K2];   // 64 KB: W1 staging, then u/w tile

    const int tid = threadIdx.x;
    {
        const float4* gw = (const float4*)W1;
        #pragma unroll
        for (int i = 0; i < 16; ++i) {
            const int c = tid + i * 256, row = c >> 5, col = (c & 31) ^ (row & 7);
            *(short8*)(&sW[row * K2 + (col << 3)]) = pack_bf16_8(gw[2 * c], gw[2 * c + 1]);
        }
    }
    __syncthreads();

    const int lane = tid & 63;
    const int wave = tid >> 6;
    const int c16  = lane & 15;
    const int q    = lane >> 4;
    const int swz  = c16 & 7;

    float b1f[8];
    #pragma unroll
    for (int t = 0; t < 8; ++t) b1f[t] = b1[t * 16 + c16];

    const floatx4 vzero = {0.f, 0.f, 0.f, 0.f};

    const int nbase = blockIdx.x * 128 + wave * 32;
    const int n0 = nbase + c16;
    const int n1 = nbase + 16 + c16;
    const int s0 = (n0 < n_nodes) ? n0 : 0;
    const int s1 = (n1 < n_nodes) ? n1 : 0;

    const float4* p0 = (const float4*)(h + (size_t)s0 * HF);
    const float4* p1 = (const float4*)(h + (size_t)s1 * HF);
    short8 a0[4], a1[4];
    #pragma unroll
    for (int f = 0; f < 4; ++f) {
        const int o = f * 8 + q * 2;
        a0[f] = pack_bf16_8(p0[o], p0[o + 1]);
        a1[f] = pack_bf16_8(p1[o], p1[o + 1]);
    }

    floatx4 au0[8], au1[8], aw0[8], aw1[8];
    #pragma unroll
    for (int t = 0; t < 8; ++t) { au0[t] = vzero; au1[t] = vzero; aw0[t] = vzero; aw1[t] = vzero; }

    #pragma unroll
    for (int ks = 0; ks < 4; ++ks) {
        #pragma unroll
        for (int t = 0; t < 8; ++t) {
            const int row = t * 16 + c16;
            const int cu = (ks * 4 + q) ^ swz;          // k in [0,128): W1a
            const int cw = 16 + ((ks * 4 + q) ^ swz);   // k in [128,256): W1b
            const short8 bu = *(const short8*)(&sW[row * K2 + (cu << 3)]);
            const short8 bw = *(const short8*)(&sW[row * K2 + (cw << 3)]);
            au0[t] = __builtin_amdgcn_mfma_f32_16x16x32_bf16(a0[ks], bu, au0[t], 0, 0, 0);
            au1[t] = __builtin_amdgcn_mfma_f32_16x16x32_bf16(a1[ks], bu, au1[t], 0, 0, 0);
            aw0[t] = __builtin_amdgcn_mfma_f32_16x16x32_bf16(a0[ks], bw, aw0[t], 0, 0, 0);
            aw1[t] = __builtin_amdgcn_mfma_f32_16x16x32_bf16(a1[ks], bw, aw1[t], 0, 0, 0);
        }
    }

    __syncthreads();   // all waves done reading W1; reuse LDS for u/w tile

    unsigned short* uL = (unsigned short*)sW + wave * 8192;
    unsigned short* wL = uL + 4096;

    #pragma unroll
    for (int r = 0; r < 4; ++r) {
        const int l0 = q * 4 + r;
        const int l1 = l0 + 16;
        #pragma unroll
        for (int t = 0; t < 8; ++t) {
            const int f = t * 16 + c16;
            uL[l0 * HF + f] = f2bf(au0[t][r] + b1f[t]);
            wL[l0 * HF + f] = f2bf(aw0[t][r]);
            uL[l1 * HF + f] = f2bf(au1[t][r] + b1f[t]);
            wL[l1 * HF + f] = f2bf(aw1[t][r]);
        }
    }
    // intra-wave LDS write->read: no barrier needed (own stripe)

    const int j   = lane & 15;
    const int sub = lane >> 4;
    #pragma unroll
    for (int il = 0; il < 8; ++il) {
        const int l = il * 4 + sub;
        const int gn = nbase + l;
        BF8 uv, wv;
        uv.v = *(const short8*)(uL + l * HF + j * 8);
        wv.v = *(const short8*)(wL + l * HF + j * 8);
        float uf[8], wf[8], mu = 0.f, mw = 0.f;
        #pragma unroll
        for (int i = 0; i < 8; ++i) {
            uf[i] = bf2f(uv.s[i]);  mu = fmaxf(mu, fabsf(uf[i]));
            wf[i] = bf2f(wv.s[i]);  mw = fmaxf(mw, fabsf(wf[i]));
        }
        #pragma unroll
        for (int off = 8; off >= 1; off >>= 1) {
            mu = fmaxf(mu, __shfl_xor(mu, off));
            mw = fmaxf(mw, __shfl_xor(mw, off));
        }
        const float iu = (mu > 0.f) ? 127.f / mu : 0.f;
        const float iw = (mw > 0.f) ? 127.f / mw : 0.f;
        if (gn < n_nodes) {
            *(uint2*)(u8 + (size_t)gn * HF + j * 8) = quant8(uf, iu);
            *(uint2*)(w8 + (size_t)gn * HF + j * 8) = quant8(wf, iw);
            if (j == 0) {
                su[gn] = mu * (1.f / 127.f);
                sw[gn] = mw * (1.f / 127.f);
            }
        }
    }
}

// ==== 2) edge phase: 8 lanes/edge, 16B int8 gathers ====
// Lane j (j in [0,8)) covers feats [j*16, j*16+16): one uint4 per row.
// Group = 8 lanes, 4 edges per group per iteration; lane 0 stores float4.
// Single sweep: block covers 32 groups x 4 edges = 128 edges.
__global__ __launch_bounds__(256) void edge_score_q8(
    const char* __restrict__ u8,
    const char* __restrict__ w8,
    const float* __restrict__ su,
    const float* __restrict__ sw,
    const int* __restrict__ src,
    const int* __restrict__ dst,
    const float* __restrict__ W2,
    const float* __restrict__ b2,
    float* __restrict__ out,
    const int n_edges)
{
    const int tid  = threadIdx.x;
    const int j    = tid & 7;
    const int grp  = (blockIdx.x * 256 + tid) >> 3;
    const int ngrp = (gridDim.x * 256) >> 3;

    float w2f[16];
    #pragma unroll
    for (int i = 0; i < 16; ++i) w2f[i] = W2[j * 16 + i];
    const float b2f = b2[0];

    for (int base = grp * 4; base < n_edges; base += ngrp * 4) {
        I16 uv[4], wv[4];
        float sU[4], sW4[4];
        int valid[4];
        #pragma unroll
        for (int k = 0; k < 4; ++k) {
            const int e = base + k;
            valid[k] = e < n_edges;
            const int s = valid[k] ? src[e] : 0;
            const int d = valid[k] ? dst[e] : 0;
            uv[k].v = *(const uint4*)(u8 + (size_t)s * HF + j * 16);
            wv[k].v = *(const uint4*)(w8 + (size_t)d * HF + j * 16);
            sU[k]  = su[s];
            sW4[k] = sw[d];
        }
        float acc[4];
        #pragma unroll
        for (int k = 0; k < 4; ++k) {
            float a = 0.f;
            #pragma unroll
            for (int i = 0; i < 16; ++i) {
                const float z = sU[k] * (float)uv[k].c[i]
                              + sW4[k] * (float)wv[k].c[i];
                a += fmaxf(z, 0.f) * w2f[i];
            }
            a += __shfl_xor(a, 1);
            a += __shfl_xor(a, 2);
            a += __shfl_xor(a, 4);
            acc[k] = a + b2f;
        }
        if (j == 0) {
            if (valid[3]) {
                *(float4*)(out + base) = make_float4(acc[0], acc[1], acc[2], acc[3]);
            } else {
                #pragma unroll
                for (int k = 0; k < 4; ++k) if (valid[k]) out[base + k] = acc[k];
            }
        }
    }
}

// =================== R6 fallback path (ws too small; kept) ===================
__global__ __launch_bounds__(256) void cvt_bf16(const float* __restrict__ src,
                                                unsigned short* __restrict__ dst,
                                                int n8) {
    int i = blockIdx.x * 256 + threadIdx.x;
    if (i < n8) {
        const float4* p = (const float4*)src + (size_t)i * 2;
        *(short8*)(dst + (size_t)i * 8) = pack_bf16_8(p[0], p[1]);
    }
}

template <bool HB16>
__global__ __launch_bounds__(256, 2) void mlp_edge(
    const void* __restrict__ hsrc,
    const int* __restrict__ src,
    const int* __restrict__ dst,
    const float* __restrict__ W1,
    const float* __restrict__ b1,
    const float* __restrict__ W2,
    const float* __restrict__ b2,
    float* __restrict__ out,
    const int n_edges,
    const int n_groups)
{
    __shared__ __hip_bfloat16 sW[HF * K2];
    const int tid = threadIdx.x;
    {
        const float4* gw = (const float4*)W1;
        #pragma unroll
        for (int i = 0; i < 16; ++i) {
            const int c = tid + i * 256, row = c >> 5, col = (c & 31) ^ (row & 7);
            *(short8*)(&sW[row * K2 + (col << 3)]) = pack_bf16_8(gw[2 * c], gw[2 * c + 1]);
        }
    }
    __syncthreads();
    const int lane = tid & 63, wave = tid >> 6;
    const int c16 = lane & 15, q = lane >> 4, swz = c16 & 7, gb = lane & 48;
    float b1f[8], w2f[8];
    #pragma unroll
    for (int t = 0; t < 8; ++t) { b1f[t] = b1[t * 16 + c16]; w2f[t] = W2[t * 16 + c16]; }
    const float b2f = b2[0];
    const floatx4 vzero = {0.f, 0.f, 0.f, 0.f};
    for (int g = blockIdx.x; g < n_groups; g += gridDim.x) {
        const int base = g * 128 + wave * 32;
        const int e0 = base + c16, e1 = base + 16 + c16;
        const int s0 = (e0 < n_edges) ? src[e0] : 0;
        const int d0 = (e0 < n_edges) ? dst[e0] : 0;
        const int s1 = (e1 < n_edges) ? src[e1] : 0;
        const int d1 = (e1 < n_edges) ? dst[e1] : 0;
        short8 a0[8], a1[8];
        if (HB16) {
            const unsigned short* hb = (const unsigned short*)hsrc;
            const short8* ps0 = (const short8*)(hb + (size_t)s0 * HF);
            const short8* pd0 = (const short8*)(hb + (size_t)d0 * HF);
            const short8* ps1 = (const short8*)(hb + (size_t)s1 * HF);
            const short8* pd1 = (const short8*)(hb + (size_t)d1 * HF);
            #pragma unroll
            for (int f = 0; f < 4; ++f) {
                a0[f] = ps0[f * 4 + q]; a0[f + 4] = pd0[f * 4 + q];
                a1[f] = ps1[f * 4 + q]; a1[f + 4] = pd1[f * 4 + q];
            }
        } else {
            const float* hf = (const float*)hsrc;
            const float4* ps0 = (const float4*)(hf + (size_t)s0 * HF);
            const float4* pd0 = (const float4*)(hf + (size_t)d0 * HF);
            const float4* ps1 = (const float4*)(hf + (size_t)s1 * HF);
            const float4* pd1 = (const float4*)(hf + (size_t)d1 * HF);
            #pragma unroll
            for (int f = 0; f < 4; ++f) {
                const int o = f * 8 + q * 2;
                a0[f]     = pack_bf16_8(ps0[o], ps0[o + 1]);
                a0[f + 4] = pack_bf16_8(pd0[o], pd0[o + 1]);
                a1[f]     = pack_bf16_8(ps1[o], ps1[o + 1]);
                a1[f + 4] = pack_bf16_8(pd1[o], pd1[o + 1]);
            }
        }
        floatx4 acc0[8], acc1[8];
        #pragma unroll
        for (int t = 0; t < 8; ++t) { acc0[t] = vzero; acc1[t] = vzero; }
        #pragma unroll
        for (int ks = 0; ks < 8; ++ks) {
            #pragma unroll
            for (int t = 0; t < 8; ++t) {
                const int chunk = (ks * 4 + q) ^ swz;
                const short8 bfr = *(const short8*)(&sW[(t * 16 + c16) * K2 + (chunk << 3)]);
                acc0[t] = __builtin_amdgcn_mfma_f32_16x16x32_bf16(a0[ks], bfr, acc0[t], 0, 0, 0);
                acc1[t] = __builtin_amdgcn_mfma_f32_16x16x32_bf16(a1[ks], bfr, acc1[t], 0, 0, 0);
            }
        }
        float p0[4] = {0.f, 0.f, 0.f, 0.f}, p1[4] = {0.f, 0.f, 0.f, 0.f};
        #pragma unroll
        for (int t = 0; t < 8; ++t)
            #pragma unroll
            for (int r = 0; r < 4; ++r) {
                p0[r] += fmaxf(acc0[t][r] + b1f[t], 0.f) * w2f[t];
                p1[r] += fmaxf(acc1[t][r] + b1f[t], 0.f) * w2f[t];
            }
        #pragma unroll
        for (int off = 8; off >= 1; off >>= 1)
            #pragma unroll
            for (int r = 0; r < 4; ++r) {
                p0[r] += __shfl(p0[r], gb | (c16 ^ off));
                p1[r] += __shfl(p1[r], gb | (c16 ^ off));
            }
        if (c16 < 4) {
            const float r0 = (c16 == 0) ? p0[0] : (c16 == 1) ? p0[1] : (c16 == 2) ? p0[2] : p0[3];
            const float r1 = (c16 == 0) ? p1[0] : (c16 == 1) ? p1[1] : (c16 == 2) ? p1[2] : p1[3];
            const int eo0 = base + q * 4 + c16, eo1 = base + 16 + q * 4 + c16;
            if (eo0 < n_edges) out[eo0] = r0 + b2f;
            if (eo1 < n_edges) out[eo1] = r1 + b2f;
        }
    }
}

extern "C" void kernel_launch(void* const* d_in, const int* in_sizes, int n_in,
                              void* d_out, int out_size, void* d_ws, size_t ws_size,
                              hipStream_t stream) {
    const float* h   = (const float*)d_in[0];
    const int*   src = (const int*)d_in[1];
    const int*   dst = (const int*)d_in[2];
    const float* W1  = (const float*)d_in[3];
    const float* b1  = (const float*)d_in[4];
    const float* W2  = (const float*)d_in[5];
    const float* b2  = (const float*)d_in[6];
    float* out = (float*)d_out;

    const int n_edges = in_sizes[1];
    const int n_nodes = in_sizes[0] / HF;
    // ws: u8 [n*128B] | w8 [n*128B] | su [n*4B] | sw [n*4B]
    const size_t row8 = (size_t)n_nodes * HF;
    const size_t need = row8 * 2 + (size_t)n_nodes * 4 * 2;

    if (ws_size >= need) {
        char*  u8 = (char*)d_ws;
        char*  w8 = u8 + row8;
        float* su = (float*)(w8 + row8);
        float* sw = su + n_nodes;

        const int ngroups = (n_nodes + 127) / 128;          // 391
        gemm_uw_f<<<dim3(ngroups), dim3(256), 0, stream>>>(h, W1, b1, u8, w8,
                                                           su, sw, n_nodes);
        // 8 lanes/edge: block = 32 groups x 4 edges = 128 edges, single sweep
        const int egrid = (n_edges + 127) / 128;            // 4688
        edge_score_q8<<<dim3(egrid), dim3(256), 0, stream>>>(u8, w8, su, sw,
                                                             src, dst, W2, b2,
                                                             out, n_edges);
    } else {
        const int n_groups = (n_edges + 127) / 128;
        int grid = 512;
        if (grid > n_groups) grid = n_groups;
        const int    h_elems  = in_sizes[0];
        const size_t hb_bytes = (size_t)h_elems * 2;
        if (ws_size >= hb_bytes && (h_elems & 7) == 0) {
            unsigned short* hb = (unsigned short*)d_ws;
            const int n8 = h_elems / 8;
            cvt_bf16<<<dim3((n8 + 255) / 256), dim3(256), 0, stream>>>(h, hb, n8);
            mlp_edge<true><<<dim3(grid), dim3(256), 0, stream>>>(
                (const void*)hb, src, dst, W1, b1, W2, b2, out, n_edges, n_groups);
        } else {
            mlp_edge<false><<<dim3(grid), dim3(256), 0, stream>>>(
                (const void*)h, src, dst, W1, b1, W2, b2, out, n_edges, n_groups);
        }
    }
}

// Round 14
// 121.009 us; speedup vs baseline: 1.0495x; 1.0495x over previous
//
#include <hip/hip_runtime.h>
#include <hip/hip_bf16.h>

// MLPPredictor: score[e] = W2 . relu(W1 @ concat(h[src],h[dst]) + b1) + b2
// SETTLED (R0-R13): h/W1/b1/W2/b2 = fp32, src/dst = int32, out = fp32.
// FINAL STRUCTURE (= R12, proven best at 122.0 us):
//   1) gemm_uw_f: per-node u = W1a@h + b1, w = W1b@h via MFMA (W1 staged bf16
//      in 64 KB XOR-swizzled LDS), then LDS-reuse epilogue: bf16 tile round-
//      trips through the dead W1 buffer, 16-lane rowmax, int8+scale to ws.
//   2) edge_score_q: 16 lanes/edge-group, 4 edges/group, 8 B int8 gathers of
//      u8[src]/w8[dst] + per-node scales, relu+dot(W2) in VALU, float4 store.
// R13 (8 lanes/edge, 16 B gathers) regressed to 127 us -> reverted; the
// 16-lane form is ~88% of the 153.6 MB / 6.5 TB/s random-gather floor.
// R10 lesson kept: quant in VGPRs spills (104 MB WRITE); LDS reuse does not.
// MFMA fragment maps (probe-verified on gfx950, R5 mode 0):
//   A: lane holds A[m=lane&15][k=(lane>>4)*8+j]
//   B: lane holds B[k=(lane>>4)*8+j][n=lane&15]
//   D: lane reg r holds D[row=(lane>>4)*4+r][col=lane&15]

typedef __attribute__((ext_vector_type(8))) short short8;   // 8 bf16
typedef __attribute__((ext_vector_type(4))) float floatx4;  // MFMA acc

constexpr int HF = 128;   // H_FEATS
constexpr int K2 = 256;   // 2*H

union BF8 { short8 v; unsigned short s[8]; __hip_bfloat16 e[8]; };

__device__ __forceinline__ short8 pack_bf16_8(float4 a, float4 b) {
    BF8 u;
    u.e[0] = __float2bfloat16(a.x); u.e[1] = __float2bfloat16(a.y);
    u.e[2] = __float2bfloat16(a.z); u.e[3] = __float2bfloat16(a.w);
    u.e[4] = __float2bfloat16(b.x); u.e[5] = __float2bfloat16(b.y);
    u.e[6] = __float2bfloat16(b.z); u.e[7] = __float2bfloat16(b.w);
    return u.v;
}

__device__ __forceinline__ float bf2f(unsigned short s) {
    union { unsigned u; float f; } c; c.u = (unsigned)s << 16; return c.f;
}

__device__ __forceinline__ unsigned short f2bf(float x) {
    return (unsigned short)__bfloat16_as_ushort(__float2bfloat16(x));
}

// pack 8 floats (|v[i]*inv| <= 127) into 8 int8 bytes (byte k = v[k])
__device__ __forceinline__ uint2 quant8(const float* v, float inv) {
    unsigned w0 = 0, w1 = 0;
    #pragma unroll
    for (int i = 0; i < 4; ++i)
        w0 |= ((unsigned)((int)rintf(v[i] * inv) & 0xFF)) << (8 * i);
    #pragma unroll
    for (int i = 0; i < 4; ++i)
        w1 |= ((unsigned)((int)rintf(v[4 + i] * inv) & 0xFF)) << (8 * i);
    return make_uint2(w0, w1);
}

// ==== 1) fused: per-node GEMM + LDS round-trip + int8 quant (R12 verbatim) ====
__global__ __launch_bounds__(256, 2) void gemm_uw_f(
    const float* __restrict__ h,
    const float* __restrict__ W1,
    const float* __restrict__ b1,
    char* __restrict__ u8,               // [n_nodes][128] int8 (u incl. +b1)
    char* __restrict__ w8,               // [n_nodes][128] int8
    float* __restrict__ su,              // [n_nodes] scale for u
    float* __restrict__ sw,              // [n_nodes] scale for w
    const int n_nodes)
{
    __shared__ __hip_bfloat16 sW[HF * K2];   // 64 KB: W1 staging, then u/w tile

    const int tid = threadIdx.x;
    {
        const float4* gw = (const float4*)W1;
        #pragma unroll
        for (int i = 0; i < 16; ++i) {
            const int c = tid + i * 256, row = c >> 5, col = (c & 31) ^ (row & 7);
            *(short8*)(&sW[row * K2 + (col << 3)]) = pack_bf16_8(gw[2 * c], gw[2 * c + 1]);
        }
    }
    __syncthreads();

    const int lane = tid & 63;
    const int wave = tid >> 6;
    const int c16  = lane & 15;
    const int q    = lane >> 4;
    const int swz  = c16 & 7;

    float b1f[8];
    #pragma unroll
    for (int t = 0; t < 8; ++t) b1f[t] = b1[t * 16 + c16];

    const floatx4 vzero = {0.f, 0.f, 0.f, 0.f};

    const int nbase = blockIdx.x * 128 + wave * 32;
    const int n0 = nbase + c16;
    const int n1 = nbase + 16 + c16;
    const int s0 = (n0 < n_nodes) ? n0 : 0;
    const int s1 = (n1 < n_nodes) ? n1 : 0;

    const float4* p0 = (const float4*)(h + (size_t)s0 * HF);
    const float4* p1 = (const float4*)(h + (size_t)s1 * HF);
    short8 a0[4], a1[4];
    #pragma unroll
    for (int f = 0; f < 4; ++f) {
        const int o = f * 8 + q * 2;
        a0[f] = pack_bf16_8(p0[o], p0[o + 1]);
        a1[f] = pack_bf16_8(p1[o], p1[o + 1]);
    }

    floatx4 au0[8], au1[8], aw0[8], aw1[8];
    #pragma unroll
    for (int t = 0; t < 8; ++t) { au0[t] = vzero; au1[t] = vzero; aw0[t] = vzero; aw1[t] = vzero; }

    #pragma unroll
    for (int ks = 0; ks < 4; ++ks) {
        #pragma unroll
        for (int t = 0; t < 8; ++t) {
            const int row = t * 16 + c16;
            const int cu = (ks * 4 + q) ^ swz;          // k in [0,128): W1a
            const int cw = 16 + ((ks * 4 + q) ^ swz);   // k in [128,256): W1b
            const short8 bu = *(const short8*)(&sW[row * K2 + (cu << 3)]);
            const short8 bw = *(const short8*)(&sW[row * K2 + (cw << 3)]);
            au0[t] = __builtin_amdgcn_mfma_f32_16x16x32_bf16(a0[ks], bu, au0[t], 0, 0, 0);
            au1[t] = __builtin_amdgcn_mfma_f32_16x16x32_bf16(a1[ks], bu, au1[t], 0, 0, 0);
            aw0[t] = __builtin_amdgcn_mfma_f32_16x16x32_bf16(a0[ks], bw, aw0[t], 0, 0, 0);
            aw1[t] = __builtin_amdgcn_mfma_f32_16x16x32_bf16(a1[ks], bw, aw1[t], 0, 0, 0);
        }
    }

    __syncthreads();   // all waves done reading W1; reuse LDS for u/w tile

    unsigned short* uL = (unsigned short*)sW + wave * 8192;
    unsigned short* wL = uL + 4096;

    #pragma unroll
    for (int r = 0; r < 4; ++r) {
        const int l0 = q * 4 + r;
        const int l1 = l0 + 16;
        #pragma unroll
        for (int t = 0; t < 8; ++t) {
            const int f = t * 16 + c16;
            uL[l0 * HF + f] = f2bf(au0[t][r] + b1f[t]);
            wL[l0 * HF + f] = f2bf(aw0[t][r]);
            uL[l1 * HF + f] = f2bf(au1[t][r] + b1f[t]);
            wL[l1 * HF + f] = f2bf(aw1[t][r]);
        }
    }
    // intra-wave LDS write->read: no barrier needed (own stripe)

    const int j   = lane & 15;
    const int sub = lane >> 4;
    #pragma unroll
    for (int il = 0; il < 8; ++il) {
        const int l = il * 4 + sub;
        const int gn = nbase + l;
        BF8 uv, wv;
        uv.v = *(const short8*)(uL + l * HF + j * 8);
        wv.v = *(const short8*)(wL + l * HF + j * 8);
        float uf[8], wf[8], mu = 0.f, mw = 0.f;
        #pragma unroll
        for (int i = 0; i < 8; ++i) {
            uf[i] = bf2f(uv.s[i]);  mu = fmaxf(mu, fabsf(uf[i]));
            wf[i] = bf2f(wv.s[i]);  mw = fmaxf(mw, fabsf(wf[i]));
        }
        #pragma unroll
        for (int off = 8; off >= 1; off >>= 1) {
            mu = fmaxf(mu, __shfl_xor(mu, off));
            mw = fmaxf(mw, __shfl_xor(mw, off));
        }
        const float iu = (mu > 0.f) ? 127.f / mu : 0.f;
        const float iw = (mw > 0.f) ? 127.f / mw : 0.f;
        if (gn < n_nodes) {
            *(uint2*)(u8 + (size_t)gn * HF + j * 8) = quant8(uf, iu);
            *(uint2*)(w8 + (size_t)gn * HF + j * 8) = quant8(wf, iw);
            if (j == 0) {
                su[gn] = mu * (1.f / 127.f);
                sw[gn] = mw * (1.f / 127.f);
            }
        }
    }
}

// ==== 2) edge phase: int8 gather + VALU (R12 verbatim, 16 lanes/edge) ====
// Lane j reads bytes [j*8, j*8+8) = feats j*8..j*8+8, so w2f[i] = W2[j*8+i].
// 4 edges per group, single-sweep grid.
__global__ __launch_bounds__(256) void edge_score_q(
    const char* __restrict__ u8,
    const char* __restrict__ w8,
    const float* __restrict__ su,
    const float* __restrict__ sw,
    const int* __restrict__ src,
    const int* __restrict__ dst,
    const float* __restrict__ W2,
    const float* __restrict__ b2,
    float* __restrict__ out,
    const int n_edges)
{
    const int tid  = threadIdx.x;
    const int j    = tid & 15;
    const int grp  = (blockIdx.x * 256 + tid) >> 4;
    const int ngrp = (gridDim.x * 256) >> 4;

    float w2f[8];
    #pragma unroll
    for (int i = 0; i < 8; ++i) w2f[i] = W2[j * 8 + i];   // natural layout
    const float b2f = b2[0];

    for (int base = grp * 4; base < n_edges; base += ngrp * 4) {
        uint2 uv[4], wv[4];
        float sU[4], sW4[4];
        int valid[4];
        #pragma unroll
        for (int k = 0; k < 4; ++k) {
            const int e = base + k;
            valid[k] = e < n_edges;
            const int s = valid[k] ? src[e] : 0;
            const int d = valid[k] ? dst[e] : 0;
            uv[k] = *(const uint2*)(u8 + (size_t)s * HF + j * 8);
            wv[k] = *(const uint2*)(w8 + (size_t)d * HF + j * 8);
            sU[k] = su[s];
            sW4[k] = sw[d];
        }
        float acc[4];
        #pragma unroll
        for (int k = 0; k < 4; ++k) {
            float a = 0.f;
            #pragma unroll
            for (int i = 0; i < 8; ++i) {
                const unsigned wu = (i < 4) ? uv[k].x : uv[k].y;
                const unsigned ww = (i < 4) ? wv[k].x : wv[k].y;
                const int sh = 8 * (i & 3);
                const float uf = (float)((signed char)((wu >> sh) & 0xFF));
                const float wf = (float)((signed char)((ww >> sh) & 0xFF));
                const float z = sU[k] * uf + sW4[k] * wf;
                a += fmaxf(z, 0.f) * w2f[i];
            }
            a += __shfl_xor(a, 1);
            a += __shfl_xor(a, 2);
            a += __shfl_xor(a, 4);
            a += __shfl_xor(a, 8);
            acc[k] = a + b2f;
        }
        if (j == 0) {
            if (valid[3]) {
                *(float4*)(out + base) = make_float4(acc[0], acc[1], acc[2], acc[3]);
            } else {
                #pragma unroll
                for (int k = 0; k < 4; ++k) if (valid[k]) out[base + k] = acc[k];
            }
        }
    }
}

// =================== R6 fallback path (ws too small; kept) ===================
__global__ __launch_bounds__(256) void cvt_bf16(const float* __restrict__ src,
                                                unsigned short* __restrict__ dst,
                                                int n8) {
    int i = blockIdx.x * 256 + threadIdx.x;
    if (i < n8) {
        const float4* p = (const float4*)src + (size_t)i * 2;
        *(short8*)(dst + (size_t)i * 8) = pack_bf16_8(p[0], p[1]);
    }
}

template <bool HB16>
__global__ __launch_bounds__(256, 2) void mlp_edge(
    const void* __restrict__ hsrc,
    const int* __restrict__ src,
    const int* __restrict__ dst,
    const float* __restrict__ W1,
    const float* __restrict__ b1,
    const float* __restrict__ W2,
    const float* __restrict__ b2,
    float* __restrict__ out,
    const int n_edges,
    const int n_groups)
{
    __shared__ __hip_bfloat16 sW[HF * K2];
    const int tid = threadIdx.x;
    {
        const float4* gw = (const float4*)W1;
        #pragma unroll
        for (int i = 0; i < 16; ++i) {
            const int c = tid + i * 256, row = c >> 5, col = (c & 31) ^ (row & 7);
            *(short8*)(&sW[row * K2 + (col << 3)]) = pack_bf16_8(gw[2 * c], gw[2 * c + 1]);
        }
    }
    __syncthreads();
    const int lane = tid & 63, wave = tid >> 6;
    const int c16 = lane & 15, q = lane >> 4, swz = c16 & 7, gb = lane & 48;
    float b1f[8], w2f[8];
    #pragma unroll
    for (int t = 0; t < 8; ++t) { b1f[t] = b1[t * 16 + c16]; w2f[t] = W2[t * 16 + c16]; }
    const float b2f = b2[0];
    const floatx4 vzero = {0.f, 0.f, 0.f, 0.f};
    for (int g = blockIdx.x; g < n_groups; g += gridDim.x) {
        const int base = g * 128 + wave * 32;
        const int e0 = base + c16, e1 = base + 16 + c16;
        const int s0 = (e0 < n_edges) ? src[e0] : 0;
        const int d0 = (e0 < n_edges) ? dst[e0] : 0;
        const int s1 = (e1 < n_edges) ? src[e1] : 0;
        const int d1 = (e1 < n_edges) ? dst[e1] : 0;
        short8 a0[8], a1[8];
        if (HB16) {
            const unsigned short* hb = (const unsigned short*)hsrc;
            const short8* ps0 = (const short8*)(hb + (size_t)s0 * HF);
            const short8* pd0 = (const short8*)(hb + (size_t)d0 * HF);
            const short8* ps1 = (const short8*)(hb + (size_t)s1 * HF);
            const short8* pd1 = (const short8*)(hb + (size_t)d1 * HF);
            #pragma unroll
            for (int f = 0; f < 4; ++f) {
                a0[f] = ps0[f * 4 + q]; a0[f + 4] = pd0[f * 4 + q];
                a1[f] = ps1[f * 4 + q]; a1[f + 4] = pd1[f * 4 + q];
            }
        } else {
            const float* hf = (const float*)hsrc;
            const float4* ps0 = (const float4*)(hf + (size_t)s0 * HF);
            const float4* pd0 = (const float4*)(hf + (size_t)d0 * HF);
            const float4* ps1 = (const float4*)(hf + (size_t)s1 * HF);
            const float4* pd1 = (const float4*)(hf + (size_t)d1 * HF);
            #pragma unroll
            for (int f = 0; f < 4; ++f) {
                const int o = f * 8 + q * 2;
                a0[f]     = pack_bf16_8(ps0[o], ps0[o + 1]);
                a0[f + 4] = pack_bf16_8(pd0[o], pd0[o + 1]);
                a1[f]     = pack_bf16_8(ps1[o], ps1[o + 1]);
                a1[f + 4] = pack_bf16_8(pd1[o], pd1[o + 1]);
            }
        }
        floatx4 acc0[8], acc1[8];
        #pragma unroll
        for (int t = 0; t < 8; ++t) { acc0[t] = vzero; acc1[t] = vzero; }
        #pragma unroll
        for (int ks = 0; ks < 8; ++ks) {
            #pragma unroll
            for (int t = 0; t < 8; ++t) {
                const int chunk = (ks * 4 + q) ^ swz;
                const short8 bfr = *(const short8*)(&sW[(t * 16 + c16) * K2 + (chunk << 3)]);
                acc0[t] = __builtin_amdgcn_mfma_f32_16x16x32_bf16(a0[ks], bfr, acc0[t], 0, 0, 0);
                acc1[t] = __builtin_amdgcn_mfma_f32_16x16x32_bf16(a1[ks], bfr, acc1[t], 0, 0, 0);
            }
        }
        float p0[4] = {0.f, 0.f, 0.f, 0.f}, p1[4] = {0.f, 0.f, 0.f, 0.f};
        #pragma unroll
        for (int t = 0; t < 8; ++t)
            #pragma unroll
            for (int r = 0; r < 4; ++r) {
                p0[r] += fmaxf(acc0[t][r] + b1f[t], 0.f) * w2f[t];
                p1[r] += fmaxf(acc1[t][r] + b1f[t], 0.f) * w2f[t];
            }
        #pragma unroll
        for (int off = 8; off >= 1; off >>= 1)
            #pragma unroll
            for (int r = 0; r < 4; ++r) {
                p0[r] += __shfl(p0[r], gb | (c16 ^ off));
                p1[r] += __shfl(p1[r], gb | (c16 ^ off));
            }
        if (c16 < 4) {
            const float r0 = (c16 == 0) ? p0[0] : (c16 == 1) ? p0[1] : (c16 == 2) ? p0[2] : p0[3];
            const float r1 = (c16 == 0) ? p1[0] : (c16 == 1) ? p1[1] : (c16 == 2) ? p1[2] : p1[3];
            const int eo0 = base + q * 4 + c16, eo1 = base + 16 + q * 4 + c16;
            if (eo0 < n_edges) out[eo0] = r0 + b2f;
            if (eo1 < n_edges) out[eo1] = r1 + b2f;
        }
    }
}

extern "C" void kernel_launch(void* const* d_in, const int* in_sizes, int n_in,
                              void* d_out, int out_size, void* d_ws, size_t ws_size,
                              hipStream_t stream) {
    const float* h   = (const float*)d_in[0];
    const int*   src = (const int*)d_in[1];
    const int*   dst = (const int*)d_in[2];
    const float* W1  = (const float*)d_in[3];
    const float* b1  = (const float*)d_in[4];
    const float* W2  = (const float*)d_in[5];
    const float* b2  = (const float*)d_in[6];
    float* out = (float*)d_out;

    const int n_edges = in_sizes[1];
    const int n_nodes = in_sizes[0] / HF;
    // ws: u8 [n*128B] | w8 [n*128B] | su [n*4B] | sw [n*4B]
    const size_t row8 = (size_t)n_nodes * HF;
    const size_t need = row8 * 2 + (size_t)n_nodes * 4 * 2;

    if (ws_size >= need) {
        char*  u8 = (char*)d_ws;
        char*  w8 = u8 + row8;
        float* su = (float*)(w8 + row8);
        float* sw = su + n_nodes;

        const int ngroups = (n_nodes + 127) / 128;          // 391
        gemm_uw_f<<<dim3(ngroups), dim3(256), 0, stream>>>(h, W1, b1, u8, w8,
                                                           su, sw, n_nodes);
        const int egrid = (n_edges + 63) / 64;              // 9375
        edge_score_q<<<dim3(egrid), dim3(256), 0, stream>>>(u8, w8, su, sw,
                                                            src, dst, W2, b2,
                                                            out, n_edges);
    } else {
        const int n_groups = (n_edges + 127) / 128;
        int grid = 512;
        if (grid > n_groups) grid = n_groups;
        const int    h_elems  = in_sizes[0];
        const size_t hb_bytes = (size_t)h_elems * 2;
        if (ws_size >= hb_bytes && (h_elems & 7) == 0) {
            unsigned short* hb = (unsigned short*)d_ws;
            const int n8 = h_elems / 8;
            cvt_bf16<<<dim3((n8 + 255) / 256), dim3(256), 0, stream>>>(h, hb, n8);
            mlp_edge<true><<<dim3(grid), dim3(256), 0, stream>>>(
                (const void*)hb, src, dst, W1, b1, W2, b2, out, n_edges, n_groups);
        } else {
            mlp_edge<false><<<dim3(grid), dim3(256), 0, stream>>>(
                (const void*)h, src, dst, W1, b1, W2, b2, out, n_edges, n_groups);
        }
    }
}